// Round 1
// baseline (3473.211 us; speedup 1.0000x reference)
//
#include <hip/hip_runtime.h>

#define N_NODES 20000
#define N_EDGES 320000
#define IN_CH 256
#define HID_CH 512

// ---------------------------------------------------------------- degree
__global__ void count_deg_kernel(const int* __restrict__ dst, float* __restrict__ deg, int E) {
    int i = blockIdx.x * blockDim.x + threadIdx.x;
    if (i < E) atomicAdd(&deg[dst[i]], 1.0f);
}

__global__ void finalize_dinv_kernel(float* deg_dinv, int N) {
    int i = blockIdx.x * blockDim.x + threadIdx.x;
    if (i < N) deg_dinv[i] = rsqrtf(deg_dinv[i] + 1.0f);
}

// ---------------------------------------------------------------- z[n,c] = x[n,c] * dinv[n]^2
__global__ void init_self_kernel(const float* __restrict__ x, const float* __restrict__ dinv,
                                 float* __restrict__ z, int N, int Cdiv4) {
    int i = blockIdx.x * blockDim.x + threadIdx.x;  // over N * C/4
    int total = N * Cdiv4;
    if (i >= total) return;
    int n = i / Cdiv4;
    float d = dinv[n];
    float s = d * d;
    float4 v = ((const float4*)x)[i];
    v.x *= s; v.y *= s; v.z *= s; v.w *= s;
    ((float4*)z)[i] = v;
}

// ---------------------------------------------------------------- edge scatter: z[dst] += h[src]*norm
template <int C>
__global__ void edge_agg_kernel(const float* __restrict__ h, const int* __restrict__ src,
                                const int* __restrict__ dst, const float* __restrict__ dinv,
                                float* __restrict__ z, int E) {
    int wave = (blockIdx.x * blockDim.x + threadIdx.x) >> 6;
    int lane = threadIdx.x & 63;
    if (wave >= E) return;
    int s = src[wave];
    int d = dst[wave];
    float norm = dinv[s] * dinv[d];
    const float4* hp = (const float4*)(h + (size_t)s * C);
    float* zp = z + (size_t)d * C;
#pragma unroll
    for (int i = 0; i < C / 256; ++i) {
        int c4 = lane + i * 64;
        float4 v = hp[c4];
        atomicAdd(&zp[c4 * 4 + 0], v.x * norm);
        atomicAdd(&zp[c4 * 4 + 1], v.y * norm);
        atomicAdd(&zp[c4 * 4 + 2], v.z * norm);
        atomicAdd(&zp[c4 * 4 + 3], v.w * norm);
    }
}

// ---------------------------------------------------------------- fp32 GEMM: C = A[M,K] @ B[K,N] + bias (+relu)
template <int K, bool RELU>
__global__ __launch_bounds__(256) void gemm_bias_kernel(const float* __restrict__ A,
                                                        const float* __restrict__ B,
                                                        const float* __restrict__ bias,
                                                        float* __restrict__ Cout, int M, int N) {
    constexpr int BM = 64, BN = 64, BK = 16;
    __shared__ float As[BK][BM + 4];  // A tile transposed: As[k][m]
    __shared__ float Bs[BK][BN + 4];
    int bm = blockIdx.x * BM;
    int bn = blockIdx.y * BN;
    int tid = threadIdx.x;
    int tx = tid & 15, ty = tid >> 4;

    float acc[4][4] = {};

    // A staging: thread t loads A[bm + t/4][k0 + (t%4)*4 .. +3] (float4)
    int ar = tid >> 2;         // 0..63
    int ac = (tid & 3) * 4;    // 0,4,8,12
    // B staging: thread t loads B[k0 + t/16][bn + (t%16)*4]
    int br = tid >> 4;         // 0..15
    int bc = (tid & 15) * 4;

    bool arow_ok = (bm + ar) < M;
    const float* Aptr = A + (size_t)(bm + (arow_ok ? ar : 0)) * K + ac;
    const float* Bptr = B + (size_t)br * N + bn + bc;

    for (int k0 = 0; k0 < K; k0 += BK) {
        float4 av = arow_ok ? *(const float4*)(Aptr + k0) : float4{0.f, 0.f, 0.f, 0.f};
        float4 bv = *(const float4*)(Bptr + (size_t)k0 * N);
        __syncthreads();
        As[ac + 0][ar] = av.x;
        As[ac + 1][ar] = av.y;
        As[ac + 2][ar] = av.z;
        As[ac + 3][ar] = av.w;
        *(float4*)&Bs[br][bc] = bv;
        __syncthreads();
#pragma unroll
        for (int kk = 0; kk < BK; ++kk) {
            float4 a4 = *(const float4*)&As[kk][ty * 4];
            float4 b4 = *(const float4*)&Bs[kk][tx * 4];
            float a[4] = {a4.x, a4.y, a4.z, a4.w};
            float b[4] = {b4.x, b4.y, b4.z, b4.w};
#pragma unroll
            for (int i = 0; i < 4; i++)
#pragma unroll
                for (int j = 0; j < 4; j++) acc[i][j] = fmaf(a[i], b[j], acc[i][j]);
        }
    }

#pragma unroll
    for (int i = 0; i < 4; i++) {
        int r = bm + ty * 4 + i;
        if (r >= M) continue;
#pragma unroll
        for (int j = 0; j < 4; j++) {
            int c = bn + tx * 4 + j;
            float v = acc[i][j] + bias[c];
            if (RELU) v = fmaxf(v, 0.f);
            Cout[(size_t)r * N + c] = v;
        }
    }
}

// ---------------------------------------------------------------- launch
extern "C" void kernel_launch(void* const* d_in, const int* in_sizes, int n_in,
                              void* d_out, int out_size, void* d_ws, size_t ws_size,
                              hipStream_t stream) {
    const float* x  = (const float*)d_in[0];
    const int*   ei = (const int*)d_in[1];
    const float* W1 = (const float*)d_in[2];
    const float* b1 = (const float*)d_in[3];
    const float* W2 = (const float*)d_in[4];
    const float* b2 = (const float*)d_in[5];
    const int* src = ei;
    const int* dst = ei + N_EDGES;

    char* ws = (char*)d_ws;
    float* dinv = (float*)ws;  // N_NODES floats (deg -> dinv in place)
    size_t off = ((size_t)N_NODES * 4 + 255) & ~(size_t)255;
    float* z1 = (float*)(ws + off);                       // [N_NODES, IN_CH]
    float* z2 = (float*)(ws + off + (size_t)N_NODES * IN_CH * 4);  // [N_NODES, HID_CH]
    float* h1 = (float*)d_out;  // reuse d_out as h1 scratch [N_NODES, HID_CH]

    // degree + dinv (shared by both layers)
    hipMemsetAsync(dinv, 0, N_NODES * sizeof(float), stream);
    count_deg_kernel<<<(N_EDGES + 255) / 256, 256, 0, stream>>>(dst, dinv, N_EDGES);
    finalize_dinv_kernel<<<(N_NODES + 255) / 256, 256, 0, stream>>>(dinv, N_NODES);

    // ---- layer 1: z1 = P @ x  (aggregate BEFORE the GEMM, 256 ch)
    init_self_kernel<<<(N_NODES * (IN_CH / 4) + 255) / 256, 256, 0, stream>>>(
        x, dinv, z1, N_NODES, IN_CH / 4);
    edge_agg_kernel<IN_CH><<<(N_EDGES + 3) / 4, 256, 0, stream>>>(x, src, dst, dinv, z1, N_EDGES);

    // h1 = relu(z1 @ W1 + b1)  -> stored in d_out (scratch)
    {
        dim3 grid((N_NODES + 63) / 64, HID_CH / 64);
        gemm_bias_kernel<IN_CH, true><<<grid, 256, 0, stream>>>(z1, W1, b1, h1, N_NODES, HID_CH);
    }

    // ---- layer 2: z2 = P @ h1 (512 ch)
    init_self_kernel<<<(N_NODES * (HID_CH / 4) + 255) / 256, 256, 0, stream>>>(
        h1, dinv, z2, N_NODES, HID_CH / 4);
    edge_agg_kernel<HID_CH><<<(N_EDGES + 3) / 4, 256, 0, stream>>>(h1, src, dst, dinv, z2, N_EDGES);

    // out = z2 @ W2 + b2  (overwrites d_out; h1 is dead by now)
    {
        dim3 grid((N_NODES + 63) / 64, HID_CH / 64);
        gemm_bias_kernel<HID_CH, false><<<grid, 256, 0, stream>>>(z2, W2, b2, (float*)d_out,
                                                                  N_NODES, HID_CH);
    }
}

// Round 2
// 446.016 us; speedup vs baseline: 7.7872x; 7.7872x over previous
//
#include <hip/hip_runtime.h>

#define N_NODES 20000
#define N_EDGES 320000
#define IN_CH 256
#define HID_CH 512

// ---------------------------------------------------------------- degree histogram (int)
__global__ void count_deg_kernel(const int* __restrict__ dst, int* __restrict__ deg, int E) {
    int i = blockIdx.x * blockDim.x + threadIdx.x;
    if (i < E) atomicAdd(&deg[dst[i]], 1);
}

__global__ void dinv_kernel(const int* __restrict__ deg, float* __restrict__ dinv, int N) {
    int i = blockIdx.x * blockDim.x + threadIdx.x;
    if (i < N) dinv[i] = rsqrtf((float)deg[i] + 1.0f);
}

// ---------------------------------------------------------------- single-block exclusive scan -> row_ptr[N+1]
__global__ __launch_bounds__(256) void scan_kernel(const int* __restrict__ deg,
                                                   int* __restrict__ row_ptr, int N) {
    __shared__ int sums[256];
    int t = threadIdx.x;
    const int CH = (N + 255) / 256;
    int base = t * CH;
    int s = 0;
    for (int i = 0; i < CH; ++i) {
        int idx = base + i;
        if (idx < N) s += deg[idx];
    }
    sums[t] = s;
    __syncthreads();
    // Hillis-Steele inclusive scan over 256 partial sums
    for (int off = 1; off < 256; off <<= 1) {
        int v = (t >= off) ? sums[t - off] : 0;
        __syncthreads();
        if (t >= off) sums[t] += v;
        __syncthreads();
    }
    int run = (t == 0) ? 0 : sums[t - 1];
    for (int i = 0; i < CH; ++i) {
        int idx = base + i;
        if (idx <= N) row_ptr[idx] = run;
        if (idx < N) run += deg[idx];
    }
}

// ---------------------------------------------------------------- bucket-scatter edges into CSR
__global__ void scatter_edges_kernel(const int* __restrict__ src, const int* __restrict__ dst,
                                     const int* __restrict__ row_ptr, int* __restrict__ cursor,
                                     int* __restrict__ esrc, int E) {
    int e = blockIdx.x * blockDim.x + threadIdx.x;
    if (e >= E) return;
    int d = dst[e];
    int pos = row_ptr[d] + atomicAdd(&cursor[d], 1);
    esrc[pos] = src[e];
}

// ---------------------------------------------------------------- gather-aggregate: z[n] = h[n]*dinv[n]^2 + sum_e h[src]*dinv[src]*dinv[n]
template <int C>
__global__ void gather_agg_kernel(const float* __restrict__ h, const int* __restrict__ esrc,
                                  const int* __restrict__ row_ptr, const float* __restrict__ dinv,
                                  float* __restrict__ z, int N) {
    constexpr int NACC = C / 256;  // float4 accumulators per lane
    int wave = (int)((blockIdx.x * blockDim.x + threadIdx.x) >> 6);
    int lane = threadIdx.x & 63;
    if (wave >= N) return;
    int n = wave;
    float dn = dinv[n];
    float self = dn * dn;
    const float4* hn = (const float4*)(h + (size_t)n * C);
    float4 acc[NACC];
#pragma unroll
    for (int i = 0; i < NACC; ++i) {
        float4 v = hn[lane + i * 64];
        acc[i] = {v.x * self, v.y * self, v.z * self, v.w * self};
    }
    int e0 = row_ptr[n], e1 = row_ptr[n + 1];
    for (int e = e0; e < e1; ++e) {
        int s = esrc[e];                 // wave-uniform broadcast load
        float norm = dinv[s] * dn;       // wave-uniform
        const float4* hs = (const float4*)(h + (size_t)s * C);
#pragma unroll
        for (int i = 0; i < NACC; ++i) {
            float4 v = hs[lane + i * 64];
            acc[i].x = fmaf(v.x, norm, acc[i].x);
            acc[i].y = fmaf(v.y, norm, acc[i].y);
            acc[i].z = fmaf(v.z, norm, acc[i].z);
            acc[i].w = fmaf(v.w, norm, acc[i].w);
        }
    }
    float4* zp = (float4*)(z + (size_t)n * C);
#pragma unroll
    for (int i = 0; i < NACC; ++i) zp[lane + i * 64] = acc[i];
}

// ---------------------------------------------------------------- fp32 GEMM: C = A[M,K] @ B[K,N] + bias (+relu)
template <int K, bool RELU>
__global__ __launch_bounds__(256) void gemm_bias_kernel(const float* __restrict__ A,
                                                        const float* __restrict__ B,
                                                        const float* __restrict__ bias,
                                                        float* __restrict__ Cout, int M, int N) {
    constexpr int BM = 64, BN = 64, BK = 16;
    __shared__ float As[BK][BM + 4];
    __shared__ float Bs[BK][BN + 4];
    int bm = blockIdx.x * BM;
    int bn = blockIdx.y * BN;
    int tid = threadIdx.x;
    int tx = tid & 15, ty = tid >> 4;

    float acc[4][4] = {};

    int ar = tid >> 2;
    int ac = (tid & 3) * 4;
    int br = tid >> 4;
    int bc = (tid & 15) * 4;

    bool arow_ok = (bm + ar) < M;
    const float* Aptr = A + (size_t)(bm + (arow_ok ? ar : 0)) * K + ac;
    const float* Bptr = B + (size_t)br * N + bn + bc;

    for (int k0 = 0; k0 < K; k0 += BK) {
        float4 av = arow_ok ? *(const float4*)(Aptr + k0) : float4{0.f, 0.f, 0.f, 0.f};
        float4 bv = *(const float4*)(Bptr + (size_t)k0 * N);
        __syncthreads();
        As[ac + 0][ar] = av.x;
        As[ac + 1][ar] = av.y;
        As[ac + 2][ar] = av.z;
        As[ac + 3][ar] = av.w;
        *(float4*)&Bs[br][bc] = bv;
        __syncthreads();
#pragma unroll
        for (int kk = 0; kk < BK; ++kk) {
            float4 a4 = *(const float4*)&As[kk][ty * 4];
            float4 b4 = *(const float4*)&Bs[kk][tx * 4];
            float a[4] = {a4.x, a4.y, a4.z, a4.w};
            float b[4] = {b4.x, b4.y, b4.z, b4.w};
#pragma unroll
            for (int i = 0; i < 4; i++)
#pragma unroll
                for (int j = 0; j < 4; j++) acc[i][j] = fmaf(a[i], b[j], acc[i][j]);
        }
    }

#pragma unroll
    for (int i = 0; i < 4; i++) {
        int r = bm + ty * 4 + i;
        if (r >= M) continue;
#pragma unroll
        for (int j = 0; j < 4; j++) {
            int c = bn + tx * 4 + j;
            float v = acc[i][j] + bias[c];
            if (RELU) v = fmaxf(v, 0.f);
            Cout[(size_t)r * N + c] = v;
        }
    }
}

// ---------------------------------------------------------------- launch
extern "C" void kernel_launch(void* const* d_in, const int* in_sizes, int n_in,
                              void* d_out, int out_size, void* d_ws, size_t ws_size,
                              hipStream_t stream) {
    const float* x  = (const float*)d_in[0];
    const int*   ei = (const int*)d_in[1];
    const float* W1 = (const float*)d_in[2];
    const float* b1 = (const float*)d_in[3];
    const float* W2 = (const float*)d_in[4];
    const float* b2 = (const float*)d_in[5];
    const int* src = ei;
    const int* dst = ei + N_EDGES;

    // workspace layout
    char* ws = (char*)d_ws;
    size_t off = 0;
    auto alloc = [&](size_t bytes) {
        void* p = ws + off;
        off = (off + bytes + 255) & ~(size_t)255;
        return p;
    };
    int*   deg     = (int*)alloc(N_NODES * 4);       // reused as cursor later
    int*   row_ptr = (int*)alloc((N_NODES + 1) * 4);
    float* dinv    = (float*)alloc(N_NODES * 4);
    int*   esrc    = (int*)alloc(N_EDGES * 4);
    float* z1      = (float*)alloc((size_t)N_NODES * IN_CH * 4);
    float* z2      = (float*)alloc((size_t)N_NODES * HID_CH * 4);
    float* h1      = (float*)d_out;  // d_out doubles as h1 scratch

    // ---- CSR build (shared by both layers)
    hipMemsetAsync(deg, 0, N_NODES * 4, stream);
    count_deg_kernel<<<(N_EDGES + 255) / 256, 256, 0, stream>>>(dst, deg, N_EDGES);
    dinv_kernel<<<(N_NODES + 255) / 256, 256, 0, stream>>>(deg, dinv, N_NODES);
    scan_kernel<<<1, 256, 0, stream>>>(deg, row_ptr, N_NODES);
    hipMemsetAsync(deg, 0, N_NODES * 4, stream);  // deg becomes cursor
    scatter_edges_kernel<<<(N_EDGES + 255) / 256, 256, 0, stream>>>(src, dst, row_ptr, deg, esrc,
                                                                    N_EDGES);

    // ---- layer 1: z1 = P @ x (aggregate BEFORE GEMM, 256 ch), h1 = relu(z1@W1+b1)
    gather_agg_kernel<IN_CH><<<(N_NODES + 3) / 4, 256, 0, stream>>>(x, esrc, row_ptr, dinv, z1,
                                                                    N_NODES);
    {
        dim3 grid((N_NODES + 63) / 64, HID_CH / 64);
        gemm_bias_kernel<IN_CH, true><<<grid, 256, 0, stream>>>(z1, W1, b1, h1, N_NODES, HID_CH);
    }

    // ---- layer 2: z2 = P @ h1 (512 ch), out = z2@W2+b2
    gather_agg_kernel<HID_CH><<<(N_NODES + 3) / 4, 256, 0, stream>>>(h1, esrc, row_ptr, dinv, z2,
                                                                     N_NODES);
    {
        dim3 grid((N_NODES + 63) / 64, HID_CH / 64);
        gemm_bias_kernel<HID_CH, false><<<grid, 256, 0, stream>>>(z2, W2, b2, (float*)d_out,
                                                                  N_NODES, HID_CH);
    }
}

// Round 3
// 310.022 us; speedup vs baseline: 11.2031x; 1.4387x over previous
//
#include <hip/hip_runtime.h>

#define N_NODES 20000
#define N_EDGES 320000
#define IN_CH 256
#define HID_CH 512

typedef unsigned short u16;
typedef __attribute__((ext_vector_type(4))) float f32x4;
typedef __attribute__((ext_vector_type(8))) short bf16x8;
typedef __attribute__((ext_vector_type(4))) u16 u16x4;

__device__ __forceinline__ float bf2f(u16 h) { return __uint_as_float((unsigned)h << 16); }
__device__ __forceinline__ u16 f2bf(float f) {  // round-to-nearest-even
    unsigned u = __float_as_uint(f);
    return (u16)((u + 0x7fffu + ((u >> 16) & 1u)) >> 16);
}

// ---------------------------------------------------------------- CSR build
__global__ void count_deg_kernel(const int* __restrict__ dst, int* __restrict__ deg, int E) {
    int i = blockIdx.x * blockDim.x + threadIdx.x;
    if (i < E) atomicAdd(&deg[dst[i]], 1);
}

__global__ void dinv_kernel(const int* __restrict__ deg, float* __restrict__ dinv, int N) {
    int i = blockIdx.x * blockDim.x + threadIdx.x;
    if (i < N) dinv[i] = rsqrtf((float)deg[i] + 1.0f);
}

__global__ __launch_bounds__(256) void scan_kernel(const int* __restrict__ deg,
                                                   int* __restrict__ row_ptr, int N) {
    __shared__ int sums[256];
    int t = threadIdx.x;
    const int CH = (N + 255) / 256;
    int base = t * CH;
    int s = 0;
    for (int i = 0; i < CH; ++i) {
        int idx = base + i;
        if (idx < N) s += deg[idx];
    }
    sums[t] = s;
    __syncthreads();
    for (int off = 1; off < 256; off <<= 1) {
        int v = (t >= off) ? sums[t - off] : 0;
        __syncthreads();
        if (t >= off) sums[t] += v;
        __syncthreads();
    }
    int run = (t == 0) ? 0 : sums[t - 1];
    for (int i = 0; i < CH; ++i) {
        int idx = base + i;
        if (idx <= N) row_ptr[idx] = run;
        if (idx < N) run += deg[idx];
    }
}

__global__ void scatter_edges_kernel(const int* __restrict__ src, const int* __restrict__ dst,
                                     const int* __restrict__ row_ptr, int* __restrict__ cursor,
                                     int* __restrict__ esrc, int E) {
    int e = blockIdx.x * blockDim.x + threadIdx.x;
    if (e >= E) return;
    int d = dst[e];
    int pos = row_ptr[d] + atomicAdd(&cursor[d], 1);
    esrc[pos] = src[e];
}

// ---------------------------------------------------------------- conversions
__global__ void f32_to_bf16_kernel(const float* __restrict__ in, u16* __restrict__ out, int n4) {
    int i = blockIdx.x * blockDim.x + threadIdx.x;
    if (i >= n4) return;
    float4 v = ((const float4*)in)[i];
    u16x4 o = {f2bf(v.x), f2bf(v.y), f2bf(v.z), f2bf(v.w)};
    ((u16x4*)out)[i] = o;
}

// W [K][N] f32 -> Wt hi/lo [N][K] bf16 (transpose + split)
template <int K>
__global__ void convert_w_kernel(const float* __restrict__ W, u16* __restrict__ hi,
                                 u16* __restrict__ lo, int N) {
    int i = blockIdx.x * blockDim.x + threadIdx.x;  // i = n*K + k (output order)
    if (i >= K * N) return;
    int n = i / K, k = i - n * K;
    float f = W[(size_t)k * N + n];
    u16 h = f2bf(f);
    hi[i] = h;
    lo[i] = f2bf(f - bf2f(h));
}

// ---------------------------------------------------------------- gather-aggregate (bf16 in, split-bf16 out)
// z[n] = h[n]*dinv[n]^2 + sum_e h[src]*dinv[src]*dinv[n]
template <int C>
__global__ void gather_agg_kernel(const u16* __restrict__ h, const int* __restrict__ esrc,
                                  const int* __restrict__ row_ptr, const float* __restrict__ dinv,
                                  u16* __restrict__ z_hi, u16* __restrict__ z_lo, int N) {
    constexpr int NV = C / 64;       // bf16 per lane (4 or 8)
    constexpr int NC = NV / 4;       // u16x4 chunks per lane
    int wave = (int)((blockIdx.x * blockDim.x + threadIdx.x) >> 6);
    int lane = threadIdx.x & 63;
    if (wave >= N) return;
    int n = wave;
    float dn = dinv[n];
    float self = dn * dn;
    float acc[NV];
    {
        const u16x4* p = (const u16x4*)(h + (size_t)n * C) + lane * NC;
#pragma unroll
        for (int c = 0; c < NC; ++c) {
            u16x4 v = p[c];
#pragma unroll
            for (int j = 0; j < 4; ++j) acc[c * 4 + j] = bf2f(v[j]) * self;
        }
    }
    int e0 = row_ptr[n], e1 = row_ptr[n + 1];
    for (int e = e0; e < e1; ++e) {
        int s = esrc[e];            // wave-uniform
        float norm = dinv[s] * dn;  // wave-uniform
        const u16x4* p = (const u16x4*)(h + (size_t)s * C) + lane * NC;
#pragma unroll
        for (int c = 0; c < NC; ++c) {
            u16x4 v = p[c];
#pragma unroll
            for (int j = 0; j < 4; ++j) acc[c * 4 + j] = fmaf(bf2f(v[j]), norm, acc[c * 4 + j]);
        }
    }
    u16x4* ph = (u16x4*)(z_hi + (size_t)n * C) + lane * NC;
    u16x4* pl = (u16x4*)(z_lo + (size_t)n * C) + lane * NC;
#pragma unroll
    for (int c = 0; c < NC; ++c) {
        u16x4 vh, vl;
#pragma unroll
        for (int j = 0; j < 4; ++j) {
            float a = acc[c * 4 + j];
            u16 hb = f2bf(a);
            vh[j] = hb;
            vl[j] = f2bf(a - bf2f(hb));
        }
        ph[c] = vh;
        pl[c] = vl;
    }
}

// ---------------------------------------------------------------- split-bf16 MFMA GEMM
// C = (Ah+Al)[M,K] @ (Bh+Bl)[K,N] + bias;  B given transposed [N][K].
// 128x128 tile, BK=64, 4 waves of 64x64, 16x16x32 MFMA, 3-term split.
template <int K, bool RELU, bool OUT_BF16>
__global__ __launch_bounds__(256) void gemm_mfma_kernel(
        const u16* __restrict__ Ah, const u16* __restrict__ Al, const u16* __restrict__ Bh,
        const u16* __restrict__ Bl, const float* __restrict__ bias, void* __restrict__ Cout,
        int M, int N) {
    __shared__ u16 lds[4 * 128 * 64];  // planes: Ah, Al, Bh, Bl  (each [128 rows][64 k], 128B rows)
    const int tid = threadIdx.x;
    const int lane = tid & 63;
    const int wid = tid >> 6;
    const int bm = blockIdx.x * 128;
    const int bn = blockIdx.y * 128;
    const int wm = (wid & 1) * 64;
    const int wn = (wid >> 1) * 64;

    f32x4 acc[4][4];
#pragma unroll
    for (int i = 0; i < 4; ++i)
#pragma unroll
        for (int j = 0; j < 4; ++j) acc[i][j] = (f32x4){0.f, 0.f, 0.f, 0.f};

    const char* ldsb = (const char*)lds;

    for (int k0 = 0; k0 < K; k0 += 64) {
        __syncthreads();  // previous compute done reading LDS
        // stage 4 planes x 16KB via global_load_lds width16; LDS dest linear,
        // source pre-swizzled with byte ^= ((row&7)<<4)  (T2, rule #21)
#pragma unroll
        for (int p = 0; p < 4; ++p) {
            const u16* base = (p == 0) ? Ah : (p == 1) ? Al : (p == 2) ? Bh : Bl;
#pragma unroll
            for (int r = 0; r < 4; ++r) {
                int chunk = r * 256 + wid * 64 + lane;  // 16B chunk id, 0..1023
                int row = chunk >> 3;                   // 8 chunks per 128B row
                int cb = (chunk & 7) << 4;
                int scb = cb ^ ((row & 7) << 4);
                int grow = (p < 2) ? min(bm + row, M - 1) : (bn + row);
                const char* src = (const char*)(base + (size_t)grow * K + k0) + scb;
                char* dst = (char*)lds + p * 16384 + ((r * 256 + wid * 64) << 4);  // wave-uniform
                __builtin_amdgcn_global_load_lds(
                    (const __attribute__((address_space(1))) void*)src,
                    (__attribute__((address_space(3))) void*)dst, 16, 0, 0);
            }
        }
        __syncthreads();  // drains vmcnt before any wave reads

#pragma unroll
        for (int kc = 0; kc < 2; ++kc) {
            bf16x8 a_h[4], a_l[4], b_h[4], b_l[4];
            int cb = (kc << 6) + ((lane >> 4) << 4);
#pragma unroll
            for (int i = 0; i < 4; ++i) {
                int ra = wm + i * 16 + (lane & 15);
                int off_a = ra * 128 + (cb ^ ((ra & 7) << 4));
                a_h[i] = *(const bf16x8*)(ldsb + off_a);
                a_l[i] = *(const bf16x8*)(ldsb + 16384 + off_a);
                int rb = wn + i * 16 + (lane & 15);
                int off_b = rb * 128 + (cb ^ ((rb & 7) << 4));
                b_h[i] = *(const bf16x8*)(ldsb + 32768 + off_b);
                b_l[i] = *(const bf16x8*)(ldsb + 49152 + off_b);
            }
#pragma unroll
            for (int i = 0; i < 4; ++i)
#pragma unroll
                for (int j = 0; j < 4; ++j) {
                    acc[i][j] = __builtin_amdgcn_mfma_f32_16x16x32_bf16(a_h[i], b_h[j], acc[i][j], 0, 0, 0);
                    acc[i][j] = __builtin_amdgcn_mfma_f32_16x16x32_bf16(a_l[i], b_h[j], acc[i][j], 0, 0, 0);
                    acc[i][j] = __builtin_amdgcn_mfma_f32_16x16x32_bf16(a_h[i], b_l[j], acc[i][j], 0, 0, 0);
                }
        }
    }

    // epilogue: C/D layout col=lane&15, row=(lane>>4)*4+t  (m89/m91 verified)
#pragma unroll
    for (int j = 0; j < 4; ++j) {
        int gc = bn + wn + j * 16 + (lane & 15);
        float bv = bias[gc];
#pragma unroll
        for (int i = 0; i < 4; ++i) {
#pragma unroll
            for (int t = 0; t < 4; ++t) {
                int gr = bm + wm + i * 16 + ((lane >> 4) << 2) + t;
                if (gr < M) {
                    float v = acc[i][j][t] + bv;
                    if (RELU) v = fmaxf(v, 0.f);
                    if (OUT_BF16)
                        ((u16*)Cout)[(size_t)gr * N + gc] = f2bf(v);
                    else
                        ((float*)Cout)[(size_t)gr * N + gc] = v;
                }
            }
        }
    }
}

// ---------------------------------------------------------------- launch
extern "C" void kernel_launch(void* const* d_in, const int* in_sizes, int n_in,
                              void* d_out, int out_size, void* d_ws, size_t ws_size,
                              hipStream_t stream) {
    const float* x  = (const float*)d_in[0];
    const int*   ei = (const int*)d_in[1];
    const float* W1 = (const float*)d_in[2];
    const float* b1 = (const float*)d_in[3];
    const float* W2 = (const float*)d_in[4];
    const float* b2 = (const float*)d_in[5];
    const int* src = ei;
    const int* dst = ei + N_EDGES;

    char* ws = (char*)d_ws;
    size_t off = 0;
    auto alloc = [&](size_t bytes) {
        void* p = ws + off;
        off = (off + bytes + 255) & ~(size_t)255;
        return p;
    };
    int*   deg     = (int*)alloc(N_NODES * 4);
    int*   row_ptr = (int*)alloc((N_NODES + 1) * 4);
    float* dinv    = (float*)alloc(N_NODES * 4);
    int*   esrc    = (int*)alloc(N_EDGES * 4);
    u16*   wt1_hi  = (u16*)alloc((size_t)IN_CH * HID_CH * 2);
    u16*   wt1_lo  = (u16*)alloc((size_t)IN_CH * HID_CH * 2);
    u16*   wt2_hi  = (u16*)alloc((size_t)HID_CH * HID_CH * 2);
    u16*   wt2_lo  = (u16*)alloc((size_t)HID_CH * HID_CH * 2);
    // overlay region: {xb, z1_hi, z1_lo} then {z2_hi, z2_lo}
    char*  R       = (char*)alloc((size_t)N_NODES * HID_CH * 2 * 2);  // 40.96 MB
    u16* xb    = (u16*)R;                                       // [N, 256]
    u16* z1_hi = (u16*)(R + (size_t)N_NODES * IN_CH * 2);       // [N, 256]
    u16* z1_lo = (u16*)(R + (size_t)N_NODES * IN_CH * 4);       // [N, 256]
    u16* z2_hi = (u16*)R;                                       // [N, 512] (over dead xb+z1_hi)
    u16* z2_lo = (u16*)(R + (size_t)N_NODES * HID_CH * 2);      // [N, 512] (over dead z1_lo)
    u16* h1    = (u16*)d_out;  // bf16 h1 scratch in d_out (dead before final GEMM writes)

    // CSR + dinv
    hipMemsetAsync(deg, 0, N_NODES * 4, stream);
    count_deg_kernel<<<(N_EDGES + 255) / 256, 256, 0, stream>>>(dst, deg, N_EDGES);
    dinv_kernel<<<(N_NODES + 255) / 256, 256, 0, stream>>>(deg, dinv, N_NODES);
    scan_kernel<<<1, 256, 0, stream>>>(deg, row_ptr, N_NODES);
    hipMemsetAsync(deg, 0, N_NODES * 4, stream);
    scatter_edges_kernel<<<(N_EDGES + 255) / 256, 256, 0, stream>>>(src, dst, row_ptr, deg, esrc,
                                                                    N_EDGES);

    // conversions
    f32_to_bf16_kernel<<<(N_NODES * IN_CH / 4 + 255) / 256, 256, 0, stream>>>(
        x, xb, N_NODES * IN_CH / 4);
    convert_w_kernel<IN_CH><<<(IN_CH * HID_CH + 255) / 256, 256, 0, stream>>>(W1, wt1_hi, wt1_lo,
                                                                              HID_CH);
    convert_w_kernel<HID_CH><<<(HID_CH * HID_CH + 255) / 256, 256, 0, stream>>>(W2, wt2_hi, wt2_lo,
                                                                                HID_CH);

    // layer 1: z1 = P @ xb ; h1 = relu(z1 @ W1 + b1)  (bf16 out)
    gather_agg_kernel<IN_CH><<<(N_NODES + 3) / 4, 256, 0, stream>>>(xb, esrc, row_ptr, dinv, z1_hi,
                                                                    z1_lo, N_NODES);
    {
        dim3 grid((N_NODES + 127) / 128, HID_CH / 128);
        gemm_mfma_kernel<IN_CH, true, true><<<grid, 256, 0, stream>>>(
            z1_hi, z1_lo, wt1_hi, wt1_lo, b1, h1, N_NODES, HID_CH);
    }

    // layer 2: z2 = P @ h1 ; out = z2 @ W2 + b2  (fp32 out)
    gather_agg_kernel<HID_CH><<<(N_NODES + 3) / 4, 256, 0, stream>>>(h1, esrc, row_ptr, dinv,
                                                                     z2_hi, z2_lo, N_NODES);
    {
        dim3 grid((N_NODES + 127) / 128, HID_CH / 128);
        gemm_mfma_kernel<HID_CH, false, false><<<grid, 256, 0, stream>>>(
            z2_hi, z2_lo, wt2_hi, wt2_lo, b2, (float*)d_out, N_NODES, HID_CH);
    }
}